// Round 1
// baseline (4358.493 us; speedup 1.0000x reference)
//
#include <hip/hip_runtime.h>
#include <hip/hip_bf16.h>

// Problem constants (fixed by the reference file)
#define PN 131072
#define PD 512
#define PK 2048

// ---------------------------------------------------------------------------
// Kernel 1: sims = X[N,D] * CB[K,D]^T  (fp32, VALU)
// 128x128 C-tile per block, BK=16, 256 threads, 8x8 micro-tile per thread.
// ---------------------------------------------------------------------------
#define BM 128
#define BN 128
#define BK 16
#define LDA (BM + 4)   // pad keeps 16B alignment (132*4B = 528B, mult of 16)

__global__ __launch_bounds__(256) void gemm_sims_kernel(
    const float* __restrict__ X, const float* __restrict__ CB,
    float* __restrict__ S) {
  __shared__ float As[BK][LDA];
  __shared__ float Bs[BK][LDA];

  const int bn = blockIdx.x;   // K-tile index (0..15)
  const int bm = blockIdx.y;   // N-tile index (0..1023)
  const int tid = threadIdx.x;
  const int tx = tid & 15;     // 0..15 -> columns
  const int ty = tid >> 4;     // 0..15 -> rows

  // staging: each thread loads 2 float4 from X and 2 from CB per K-tile
  const int ar = tid >> 2;         // 0..63 (row within tile half)
  const int ak = (tid & 3) * 4;    // 0,4,8,12 (k offset)

  const float* Aptr = X + (size_t)(bm * BM + ar) * PD + ak;
  const float* Bptr = CB + (size_t)(bn * BN + ar) * PD + ak;

  float acc[8][8];
#pragma unroll
  for (int i = 0; i < 8; ++i)
#pragma unroll
    for (int j = 0; j < 8; ++j) acc[i][j] = 0.0f;

  for (int kt = 0; kt < PD; kt += BK) {
    float4 a0 = *(const float4*)(Aptr + kt);
    float4 a1 = *(const float4*)(Aptr + kt + (size_t)64 * PD);
    float4 b0 = *(const float4*)(Bptr + kt);
    float4 b1 = *(const float4*)(Bptr + kt + (size_t)64 * PD);

    __syncthreads();  // previous iteration's LDS reads must be done

    As[ak + 0][ar] = a0.x; As[ak + 1][ar] = a0.y;
    As[ak + 2][ar] = a0.z; As[ak + 3][ar] = a0.w;
    As[ak + 0][ar + 64] = a1.x; As[ak + 1][ar + 64] = a1.y;
    As[ak + 2][ar + 64] = a1.z; As[ak + 3][ar + 64] = a1.w;

    Bs[ak + 0][ar] = b0.x; Bs[ak + 1][ar] = b0.y;
    Bs[ak + 2][ar] = b0.z; Bs[ak + 3][ar] = b0.w;
    Bs[ak + 0][ar + 64] = b1.x; Bs[ak + 1][ar + 64] = b1.y;
    Bs[ak + 2][ar + 64] = b1.z; Bs[ak + 3][ar + 64] = b1.w;

    __syncthreads();

#pragma unroll
    for (int k = 0; k < BK; ++k) {
      float a_frag[8], b_frag[8];
      float4 t;
      t = *(const float4*)&As[k][ty * 4];
      a_frag[0] = t.x; a_frag[1] = t.y; a_frag[2] = t.z; a_frag[3] = t.w;
      t = *(const float4*)&As[k][64 + ty * 4];
      a_frag[4] = t.x; a_frag[5] = t.y; a_frag[6] = t.z; a_frag[7] = t.w;
      t = *(const float4*)&Bs[k][tx * 4];
      b_frag[0] = t.x; b_frag[1] = t.y; b_frag[2] = t.z; b_frag[3] = t.w;
      t = *(const float4*)&Bs[k][64 + tx * 4];
      b_frag[4] = t.x; b_frag[5] = t.y; b_frag[6] = t.z; b_frag[7] = t.w;

#pragma unroll
      for (int i = 0; i < 8; ++i)
#pragma unroll
        for (int j = 0; j < 8; ++j)
          acc[i][j] = fmaf(a_frag[i], b_frag[j], acc[i][j]);
    }
  }

  // epilogue: coalesced float4 stores
#pragma unroll
  for (int i = 0; i < 8; ++i) {
    const int rm = bm * BM + ((i < 4) ? (ty * 4 + i) : (64 + ty * 4 + i - 4));
    float* c = S + (size_t)rm * PK + bn * BN;
    *(float4*)(c + tx * 4) =
        make_float4(acc[i][0], acc[i][1], acc[i][2], acc[i][3]);
    *(float4*)(c + 64 + tx * 4) =
        make_float4(acc[i][4], acc[i][5], acc[i][6], acc[i][7]);
  }
}

// ---------------------------------------------------------------------------
// Kernel 2: per-row argmax over K=2048 (numpy first-occurrence tie-break),
// write label as float, gather codebook row into preds.
// One 256-thread block per row.
// ---------------------------------------------------------------------------
__global__ __launch_bounds__(256) void argmax_gather_kernel(
    const float* __restrict__ S, const float* __restrict__ CB,
    float* __restrict__ preds, float* __restrict__ labels) {
  const int row = blockIdx.x;
  const float* s = S + (size_t)row * PK;
  const int tid = threadIdx.x;

  float best = -3.402823466e+38f;
  int bi = PK;  // sentinel larger than any real index
#pragma unroll
  for (int it = 0; it < PK / 256; ++it) {
    const int j = tid + it * 256;
    const float v = s[j];
    if (v > best) { best = v; bi = j; }  // strict > keeps first occurrence
  }

  // wave (64-lane) reduction
#pragma unroll
  for (int off = 32; off > 0; off >>= 1) {
    const float ov = __shfl_down(best, off, 64);
    const int oi = __shfl_down(bi, off, 64);
    if (ov > best || (ov == best && oi < bi)) { best = ov; bi = oi; }
  }

  __shared__ float sv[4];
  __shared__ int si[4];
  __shared__ int final_idx;
  const int wave = tid >> 6;
  if ((tid & 63) == 0) { sv[wave] = best; si[wave] = bi; }
  __syncthreads();
  if (tid == 0) {
    best = sv[0]; bi = si[0];
#pragma unroll
    for (int w = 1; w < 4; ++w) {
      if (sv[w] > best || (sv[w] == best && si[w] < bi)) {
        best = sv[w]; bi = si[w];
      }
    }
    final_idx = bi;
    labels[row] = (float)bi;
  }
  __syncthreads();

  const int lbl = final_idx;
  const float4* src = (const float4*)(CB + (size_t)lbl * PD);
  float4* dst = (float4*)(preds + (size_t)row * PD);
  if (tid < PD / 4) dst[tid] = src[tid];  // 128 float4 = 512 floats
}

// ---------------------------------------------------------------------------
extern "C" void kernel_launch(void* const* d_in, const int* in_sizes, int n_in,
                              void* d_out, int out_size, void* d_ws,
                              size_t ws_size, hipStream_t stream) {
  const float* X = (const float*)d_in[0];    // [N, D]
  const float* CB = (const float*)d_in[1];   // [K, D]

  float* preds = (float*)d_out;                      // [N, D]
  float* labels = preds + (size_t)PN * PD;           // [N]
  float* sims = labels + PN;                         // [N, K]

  dim3 g1(PK / BN, PN / BM);  // (16, 1024)
  gemm_sims_kernel<<<g1, 256, 0, stream>>>(X, CB, sims);
  argmax_gather_kernel<<<PN, 256, 0, stream>>>(sims, CB, preds, labels);
}